// Round 11
// baseline (103.674 us; speedup 1.0000x reference)
//
#include <hip/hip_runtime.h>

typedef unsigned short u16;
typedef unsigned int u32;
typedef __attribute__((ext_vector_type(2))) unsigned int u32x2;
typedef __attribute__((ext_vector_type(4))) unsigned short u16x4;
typedef __attribute__((ext_vector_type(8))) short short8;
typedef __attribute__((ext_vector_type(4))) float f32x4;

#define MFMA16(a, b, c) __builtin_amdgcn_mfma_f32_16x16x32_bf16(a, b, c, 0, 0, 0)

__device__ __forceinline__ u16 f2bf(float f) {
  unsigned u = __builtin_bit_cast(unsigned, f);
  u += 0x7fffu + ((u >> 16) & 1u);
  return (u16)(u >> 16);
}

__device__ __forceinline__ float bf2f(u16 b) {
  return __builtin_bit_cast(float, ((u32)b) << 16);
}

__device__ __forceinline__ u32 cvtpk(float lo, float hi) {
  u32 r;
  asm("v_cvt_pk_bf16_f32 %0, %1, %2" : "=v"(r) : "v"(lo), "v"(hi));
  return r;
}

__device__ __forceinline__ float ex2(float x) {  // 2^x
  float r;
  asm("v_exp_f32 %0, %1" : "=v"(r) : "v"(x));
  return r;
}

__device__ __forceinline__ void gl_lds16(const void* g, void* l) {
  __builtin_amdgcn_global_load_lds((const __attribute__((address_space(1))) char*)g,
                                   (__attribute__((address_space(3))) char*)l, 16, 0, 0);
}

// ---------------- f32 -> bf16 convert (query + kv in one dispatch) ----------------
__global__ __launch_bounds__(256) void cvt2_k(const float* __restrict__ a,
                                              const float* __restrict__ b,
                                              u16* __restrict__ oa, u16* __restrict__ ob) {
  const int bid = blockIdx.x;
  const float* in = (bid < 4096) ? a : b;
  u16* out = (bid < 4096) ? oa : ob;
  int i = (bid & 4095) * 256 + threadIdx.x;
  float4 v = ((const float4*)in)[i];
  u16x4 o;
  o.x = f2bf(v.x); o.y = f2bf(v.y); o.z = f2bf(v.z); o.w = f2bf(v.w);
  ((u16x4*)out)[i] = o;
}

// ---------------- W[k][n] f32 -> Wt[n][k] bf16 (tiled transpose) ----------------
__global__ __launch_bounds__(256) void wt_k(const float* __restrict__ W0, const float* __restrict__ W1,
                                            const float* __restrict__ W2, const float* __restrict__ W3,
                                            u16* __restrict__ T0, u16* __restrict__ T1,
                                            u16* __restrict__ T2, u16* __restrict__ T3) {
  const float* W; u16* T;
  switch (blockIdx.z) {
    case 0: W = W0; T = T0; break;
    case 1: W = W1; T = T1; break;
    case 2: W = W2; T = T2; break;
    default: W = W3; T = T3; break;
  }
  __shared__ __align__(16) u16 t[64][72];
  const int k0 = blockIdx.y * 64, n0 = blockIdx.x * 64;
  const int tid = threadIdx.x;
  const int r = tid >> 4, c4 = (tid & 15) * 4;
#pragma unroll
  for (int i = 0; i < 4; i++) {
    float4 v = *(const float4*)(W + (k0 + r + i * 16) * 1024 + n0 + c4);
    u16x4 o;
    o.x = f2bf(v.x); o.y = f2bf(v.y); o.z = f2bf(v.z); o.w = f2bf(v.w);
    *(u16x4*)&t[r + i * 16][c4] = o;
  }
  __syncthreads();
#pragma unroll
  for (int i = 0; i < 4; i++) {
    int nr = r + i * 16;
    u16x4 o;
    o.x = t[c4 + 0][nr]; o.y = t[c4 + 1][nr]; o.z = t[c4 + 2][nr]; o.w = t[c4 + 3][nr];
    *(u16x4*)(T + (n0 + nr) * 1024 + k0 + c4) = o;
  }
}

// ---------------- fused QKV projection, 128x128 tile, BK=32 double-buffered ----------------
// Counted-vmcnt pipeline: issue stage(t+1) -> vmcnt(4) -> bar -> 16 MFMA -> bar.
// z=0: Q -> Qh bf16 [B][H][1024][64] scaled 0.125*log2(e); z=1: K; z=2: V^T.
__global__ __launch_bounds__(256, 3) void gemmqkv_k(
    const u16* __restrict__ qbf, const u16* __restrict__ kvbf,
    const u16* __restrict__ Wqt, const u16* __restrict__ Wkt, const u16* __restrict__ Wvt,
    const float* __restrict__ pbq, const float* __restrict__ pbk, const float* __restrict__ pbv,
    u16* __restrict__ Qh, u16* __restrict__ Kh, u16* __restrict__ Vth) {
  const int lin = blockIdx.x;
  const int swz = (lin & 7) * 96 + (lin >> 3);
  const int x = swz & 7, y = (swz >> 3) & 31, z = swz >> 8;

  const u16* A  = (z == 0) ? qbf : kvbf;
  const u16* Bt = (z == 0) ? Wqt : (z == 1 ? Wkt : Wvt);
  const float* bias = (z == 0) ? pbq : (z == 1 ? pbk : pbv);

  __shared__ __align__(16) u16 As[2 * 128 * 32];  // 16 KB (dbuf)
  __shared__ __align__(16) u16 Bs[2 * 128 * 32];  // 16 KB (dbuf)
  const int tid = threadIdx.x;
  const int l = tid & 63, w = tid >> 6;
  const int lr = l >> 4, lc = l & 15;
  const int wr = w >> 1, wc = w & 1;
  const int m0 = y * 128, n0 = x * 128;

  f32x4 acc[4][4] = {};

  const int sr = tid >> 2, sc = (tid & 3) * 8;
  const u16* Ag = A + (m0 + sr) * 1024 + sc;
  const u16* Bg = Bt + (n0 + sr) * 1024 + sc;

  // prologue: stage tile 0 into buffer 0
  gl_lds16(Ag, As + tid * 8);
  gl_lds16(Ag + 64 * 1024, As + 2048 + tid * 8);
  gl_lds16(Bg, Bs + tid * 8);
  gl_lds16(Bg + 64 * 1024, Bs + 2048 + tid * 8);

  for (int t = 0; t < 32; ++t) {
    const int pb = t & 1;
    if (t < 31) {
      const int kn = (t + 1) * 32;
      u16* AsN = As + (pb ^ 1) * 4096;
      u16* BsN = Bs + (pb ^ 1) * 4096;
      gl_lds16(Ag + kn, AsN + tid * 8);
      gl_lds16(Ag + 64 * 1024 + kn, AsN + 2048 + tid * 8);
      gl_lds16(Bg + kn, BsN + tid * 8);
      gl_lds16(Bg + 64 * 1024 + kn, BsN + 2048 + tid * 8);
      asm volatile("s_waitcnt vmcnt(4)" ::: "memory");  // tile t landed; t+1 in flight
    } else {
      asm volatile("s_waitcnt vmcnt(0)" ::: "memory");
    }
    __builtin_amdgcn_s_barrier();
    asm volatile("" ::: "memory");

    const u16* PA = ((z == 2) ? Bs : As) + pb * 4096;
    const u16* PB = ((z == 2) ? As : Bs) + pb * 4096;
    short8 af[4], bf[4];
    const int ks8 = lr * 8;
#pragma unroll
    for (int m = 0; m < 4; m++)
      af[m] = *(const short8*)(PA + (wr * 64 + m * 16 + lc) * 32 + ks8);
#pragma unroll
    for (int n = 0; n < 4; n++)
      bf[n] = *(const short8*)(PB + (wc * 64 + n * 16 + lc) * 32 + ks8);
    __builtin_amdgcn_s_setprio(1);
#pragma unroll
    for (int m = 0; m < 4; m++)
#pragma unroll
      for (int n = 0; n < 4; n++)
        acc[m][n] = MFMA16(af[m], bf[n], acc[m][n]);
    __builtin_amdgcn_s_setprio(0);

    asm volatile("" ::: "memory");
    __builtin_amdgcn_s_barrier();   // all waves done reading buf pb (t+1 stage targets pb^1)
  }

  if (z == 2) {  // V^T: acc rows = channel, cols = token
#pragma unroll
    for (int m = 0; m < 4; m++) {
#pragma unroll
      for (int r = 0; r < 4; r++) {
        int ncol = n0 + wr * 64 + m * 16 + lr * 4 + r;
        float bb = bias[ncol];
        int h = ncol >> 6, d = ncol & 63;
#pragma unroll
        for (int n = 0; n < 4; n++) {
          int tok = m0 + wc * 64 + n * 16 + lc;
          Vth[(((tok >> 10) * 16 + h) * 64 + d) * 1024 + (tok & 1023)] =
              f2bf(acc[m][n][r] + bb);
        }
      }
    }
  } else {
    u16* outb = (z == 0) ? Qh : Kh;
    const float scale = (z == 0) ? 0.18033688f : 1.0f;  // 0.125 * log2(e)
#pragma unroll
    for (int m = 0; m < 4; m++)
#pragma unroll
      for (int n = 0; n < 4; n++) {
        int ncol = n0 + wc * 64 + n * 16 + lc;
        float bb = bias[ncol];
        int h = ncol >> 6, d = ncol & 63;
#pragma unroll
        for (int r = 0; r < 4; r++) {
          int tok = m0 + wr * 64 + m * 16 + lr * 4 + r;
          outb[(((tok >> 10) * 16 + h) * 1024 + (tok & 1023)) * 64 + d] =
              f2bf((acc[m][n][r] + bb) * scale);
        }
      }
  }
}

// ---------------- output projection, 128x64 tile, BK=64 double-buffered -> bf16 ----------------
__global__ __launch_bounds__(256, 2) void gemmo_k(const u16* __restrict__ A,
                                                  const u16* __restrict__ Bt,
                                                  const float* __restrict__ bias,
                                                  u16* __restrict__ outb) {
  const int lin = blockIdx.x;
  const int swz = (lin & 7) * 64 + (lin >> 3);
  const int x = swz & 15, y = swz >> 4;

  __shared__ __align__(16) u16 As[2 * 128 * 64];  // 32 KB dbuf; halves [128][32]
  __shared__ __align__(16) u16 Bs[2 * 64 * 64];   // 16 KB dbuf; halves [64][32]
  const int tid = threadIdx.x;
  const int l = tid & 63, w = tid >> 6;
  const int lr = l >> 4, lc = l & 15;
  const int wr = w >> 1, wc = w & 1;
  const int m0 = y * 128, n0 = x * 64;

  f32x4 acc[4][2] = {};
  const int sc = (tid & 3) * 8;
  const u16* Ag = A + (m0 + (tid >> 2)) * 1024 + sc;
  const u16* Bg = Bt + (n0 + (tid >> 2)) * 1024 + sc;

  // prologue: stage tile 0 into buffer 0
  gl_lds16(Ag, As + tid * 8);
  gl_lds16(Ag + 64 * 1024, As + 2048 + tid * 8);
  gl_lds16(Ag + 32, As + 4096 + tid * 8);
  gl_lds16(Ag + 64 * 1024 + 32, As + 6144 + tid * 8);
  gl_lds16(Bg, Bs + tid * 8);
  gl_lds16(Bg + 32, Bs + 2048 + tid * 8);

  for (int t = 0; t < 16; ++t) {
    const int pb = t & 1;
    if (t < 15) {
      const int kn = (t + 1) * 64;
      u16* AsN = As + (pb ^ 1) * 8192;
      u16* BsN = Bs + (pb ^ 1) * 4096;
      gl_lds16(Ag + kn, AsN + tid * 8);
      gl_lds16(Ag + 64 * 1024 + kn, AsN + 2048 + tid * 8);
      gl_lds16(Ag + kn + 32, AsN + 4096 + tid * 8);
      gl_lds16(Ag + 64 * 1024 + kn + 32, AsN + 6144 + tid * 8);
      gl_lds16(Bg + kn, BsN + tid * 8);
      gl_lds16(Bg + kn + 32, BsN + 2048 + tid * 8);
      asm volatile("s_waitcnt vmcnt(6)" ::: "memory");  // tile t landed; t+1 in flight
    } else {
      asm volatile("s_waitcnt vmcnt(0)" ::: "memory");
    }
    __builtin_amdgcn_s_barrier();
    asm volatile("" ::: "memory");

    const u16* PA = As + pb * 8192;
    const u16* PB = Bs + pb * 4096;
    short8 af[4][2], bf[2][2];
    const int ks8 = lr * 8;
#pragma unroll
    for (int m = 0; m < 4; m++)
#pragma unroll
      for (int h = 0; h < 2; h++)
        af[m][h] = *(const short8*)(PA + h * 4096 + (wr * 64 + m * 16 + lc) * 32 + ks8);
#pragma unroll
    for (int n = 0; n < 2; n++)
#pragma unroll
      for (int h = 0; h < 2; h++)
        bf[n][h] = *(const short8*)(PB + h * 2048 + (wc * 32 + n * 16 + lc) * 32 + ks8);
    __builtin_amdgcn_s_setprio(1);
#pragma unroll
    for (int m = 0; m < 4; m++)
#pragma unroll
      for (int n = 0; n < 2; n++) {
        acc[m][n] = MFMA16(af[m][0], bf[n][0], acc[m][n]);
        acc[m][n] = MFMA16(af[m][1], bf[n][1], acc[m][n]);
      }
    __builtin_amdgcn_s_setprio(0);

    asm volatile("" ::: "memory");
    __builtin_amdgcn_s_barrier();
  }
#pragma unroll
  for (int m = 0; m < 4; m++)
#pragma unroll
    for (int n = 0; n < 2; n++) {
      int ncol = n0 + wc * 32 + n * 16 + lc;
      float bb = bias[ncol];
#pragma unroll
      for (int r = 0; r < 4; r++) {
        int tok = m0 + wr * 64 + m * 16 + lr * 4 + r;
        outb[tok * 1024 + ncol] = f2bf(acc[m][n][r] + bb);
      }
    }
}

// ---------------- flash attention: QBLK=128, zero hot-path shuffles ----------------
__global__ __launch_bounds__(256, 2) void attn_k(const u16* __restrict__ Q,
                                                 const u16* __restrict__ K,
                                                 const u16* __restrict__ Vt,
                                                 u16* __restrict__ O) {
  const int bid = blockIdx.x;          // 512 blocks
  const int xcd = bid & 7, j = bid >> 3;
  const int bh = xcd + 8 * (j & 7);    // 8 heads per XCD
  const int q0 = (j >> 3) * 128;       // 8 q-blocks of 128
  const int tid = threadIdx.x;
  const int w = tid >> 6, l = tid & 63;
  const int lr = l >> 4, lc = l & 15;
  const u16* Qh = Q + bh * (1024 * 64);
  const u16* Kh = K + bh * (1024 * 64);
  const u16* Vh = Vt + bh * (64 * 1024);

  __shared__ __align__(16) u16 Ks[2][64 * 64];      // 16 KB
  __shared__ __align__(16) u16 Vs[2][64 * 64];      // 16 KB
  __shared__ __align__(16) u32 Plds[4][2][16][32];  // 16 KB, XOR-swizzled slots

  const int st_row = tid >> 3;
  const int st_cb = (tid & 7) * 16;
  const int sw1 = (st_cb ^ ((st_row & 7) << 4)) >> 1;
  const int st_row2 = st_row + 32;
  const int sw2 = (st_cb ^ ((st_row2 & 7) << 4)) >> 1;

  // Q fragments: 2 q-groups x 2 k-slices
  short8 bq[2][2];
#pragma unroll
  for (int g = 0; g < 2; g++)
#pragma unroll
    for (int ks = 0; ks < 2; ks++)
      bq[g][ks] = *(const short8*)(Qh + (q0 + w * 32 + g * 16 + lc) * 64 + ks * 32 + lr * 8);

  f32x4 oacc[2][4] = {};
  float mrun[2] = {-1e30f, -1e30f};   // per-q running max (log2 domain)
  float lrun[2] = {0.f, 0.f};         // per-lane partial sum (reduced in epilogue)

  // prologue: stage tile 0 into buffer 0
  gl_lds16(Kh + st_row * 64 + sw1, &Ks[0][tid * 8]);
  gl_lds16(Kh + st_row2 * 64 + sw2, &Ks[0][2048 + tid * 8]);
  gl_lds16(Vh + st_row * 1024 + sw1, &Vs[0][tid * 8]);
  gl_lds16(Vh + st_row2 * 1024 + sw2, &Vs[0][2048 + tid * 8]);

  const int xw = (lc & 7) << 2;  // P-LDS XOR

  for (int t = 0; t < 16; ++t) {
    const int pb = t & 1;
    if (t < 15) {
      const int kvn = (t + 1) * 64;
      gl_lds16(Kh + (kvn + st_row) * 64 + sw1, &Ks[pb ^ 1][tid * 8]);
      gl_lds16(Kh + (kvn + st_row2) * 64 + sw2, &Ks[pb ^ 1][2048 + tid * 8]);
      gl_lds16(Vh + st_row * 1024 + kvn + sw1, &Vs[pb ^ 1][tid * 8]);
      gl_lds16(Vh + st_row2 * 1024 + kvn + sw2, &Vs[pb ^ 1][2048 + tid * 8]);
      asm volatile("s_waitcnt vmcnt(4)" ::: "memory");  // tile t landed; t+1 in flight
    } else {
      asm volatile("s_waitcnt vmcnt(0)" ::: "memory");
    }
    __builtin_amdgcn_s_barrier();
    asm volatile("" ::: "memory");

    const u16* Kb = Ks[pb];
    const u16* Vb = Vs[pb];

    // S^T = K . Q^T for both q-groups; each K fragment read feeds 2 MFMAs
    f32x4 s0[4] = {}, s1[4] = {};
    __builtin_amdgcn_s_setprio(1);
#pragma unroll
    for (int mk = 0; mk < 4; mk++) {
      const int krow = mk * 16 + lc;
      const u16* kp = Kb + krow * 64;
#pragma unroll
      for (int ks = 0; ks < 2; ks++) {
        const int cb = (ks * 64 + lr * 16) ^ ((krow & 7) << 4);
        short8 ak = *(const short8*)(kp + (cb >> 1));
        s0[mk] = MFMA16(ak, bq[0][ks], s0[mk]);
        s1[mk] = MFMA16(ak, bq[1][ks], s1[mk]);
      }
    }
    __builtin_amdgcn_s_setprio(0);

    // per-lane local max over own 16 values (tree, no shuffles)
    float mx0, mx1;
    {
      float a = fmaxf(fmaxf(s0[0][0], s0[0][1]), fmaxf(s0[0][2], s0[0][3]));
      float b = fmaxf(fmaxf(s0[1][0], s0[1][1]), fmaxf(s0[1][2], s0[1][3]));
      float c = fmaxf(fmaxf(s0[2][0], s0[2][1]), fmaxf(s0[2][2], s0[2][3]));
      float d = fmaxf(fmaxf(s0[3][0], s0[3][1]), fmaxf(s0[3][2], s0[3][3]));
      mx0 = fmaxf(fmaxf(a, b), fmaxf(c, d));
      float e = fmaxf(fmaxf(s1[0][0], s1[0][1]), fmaxf(s1[0][2], s1[0][3]));
      float f = fmaxf(fmaxf(s1[1][0], s1[1][1]), fmaxf(s1[1][2], s1[1][3]));
      float g2 = fmaxf(fmaxf(s1[2][0], s1[2][1]), fmaxf(s1[2][2], s1[2][3]));
      float h = fmaxf(fmaxf(s1[3][0], s1[3][1]), fmaxf(s1[3][2], s1[3][3]));
      mx1 = fmaxf(fmaxf(e, f), fmaxf(g2, h));
    }

    // shuffle-free defer-max: decision via __all on per-lane maxima.
    if (!__all(mx0 <= mrun[0] + 8.f && mx1 <= mrun[1] + 8.f)) {
      mx0 = fmaxf(mx0, __shfl_xor(mx0, 16));
      mx0 = fmaxf(mx0, __shfl_xor(mx0, 32));
      mx1 = fmaxf(mx1, __shfl_xor(mx1, 16));
      mx1 = fmaxf(mx1, __shfl_xor(mx1, 32));
      float mn0 = fmaxf(mrun[0], mx0), mn1 = fmaxf(mrun[1], mx1);
      float al0 = ex2(mrun[0] - mn0), al1 = ex2(mrun[1] - mn1);
      mrun[0] = mn0; mrun[1] = mn1;
      lrun[0] *= al0; lrun[1] *= al1;
      float a0[4], a1[4];
#pragma unroll
      for (int r = 0; r < 4; r++) {
        a0[r] = __shfl(al0, lr * 4 + r);
        a1[r] = __shfl(al1, lr * 4 + r);
      }
#pragma unroll
      for (int nd = 0; nd < 4; nd++)
#pragma unroll
        for (int r = 0; r < 4; r++) {
          oacc[0][nd][r] *= a0[r];
          oacc[1][nd][r] *= a1[r];
        }
    }

    // P = 2^(S - m); accumulate per-lane partial sums (no shuffles)
#pragma unroll
    for (int mk = 0; mk < 4; mk++)
#pragma unroll
      for (int r = 0; r < 4; r++) {
        s0[mk][r] = ex2(s0[mk][r] - mrun[0]);
        s1[mk][r] = ex2(s1[mk][r] - mrun[1]);
      }
    {
      float a = (s0[0][0] + s0[0][1]) + (s0[0][2] + s0[0][3]);
      float b = (s0[1][0] + s0[1][1]) + (s0[1][2] + s0[1][3]);
      float c = (s0[2][0] + s0[2][1]) + (s0[2][2] + s0[2][3]);
      float d = (s0[3][0] + s0[3][1]) + (s0[3][2] + s0[3][3]);
      lrun[0] += (a + b) + (c + d);
      float e = (s1[0][0] + s1[0][1]) + (s1[0][2] + s1[0][3]);
      float f = (s1[1][0] + s1[1][1]) + (s1[1][2] + s1[1][3]);
      float g2 = (s1[2][0] + s1[2][1]) + (s1[2][2] + s1[2][3]);
      float h = (s1[3][0] + s1[3][1]) + (s1[3][2] + s1[3][3]);
      lrun[1] += (e + f) + (g2 + h);
    }

    // pack P -> per-wave LDS, b64 writes
    u32* PW0 = &Plds[w][0][lc][0];
    u32* PW1 = &Plds[w][1][lc][0];
#pragma unroll
    for (int mk = 0; mk < 4; mk++) {
      const int idx = (mk * 8 + lr * 2) ^ xw;
      u32x2 p0 = {cvtpk(s0[mk][0], s0[mk][1]), cvtpk(s0[mk][2], s0[mk][3])};
      u32x2 p1 = {cvtpk(s1[mk][0], s1[mk][1]), cvtpk(s1[mk][2], s1[mk][3])};
      *(u32x2*)&PW0[idx] = p0;
      *(u32x2*)&PW1[idx] = p1;
    }

    // O += P V ; each V fragment read feeds 2 MFMAs
    __builtin_amdgcn_s_setprio(1);
#pragma unroll
    for (int ks = 0; ks < 2; ks++) {
      short8 ap0 = *(const short8*)&Plds[w][0][lc][(ks * 16 + lr * 4) ^ xw];
      short8 ap1 = *(const short8*)&Plds[w][1][lc][(ks * 16 + lr * 4) ^ xw];
#pragma unroll
      for (int nd = 0; nd < 4; nd++) {
        const int vrow = nd * 16 + lc;
        const int cb = (ks * 64 + lr * 16) ^ ((vrow & 7) << 4);
        short8 bv = *(const short8*)(Vb + vrow * 64 + (cb >> 1));
        oacc[0][nd] = MFMA16(ap0, bv, oacc[0][nd]);
        oacc[1][nd] = MFMA16(ap1, bv, oacc[1][nd]);
      }
    }
    __builtin_amdgcn_s_setprio(0);

    asm volatile("" ::: "memory");
    __builtin_amdgcn_s_barrier();  // all waves done reading Ks[pb]/Vs[pb]
  }

  // epilogue: reduce per-lane partial sums across hi-groups, then normalize
  const int b = bh >> 4, h = bh & 15;
#pragma unroll
  for (int g = 0; g < 2; g++) {
    float lsum = lrun[g];
    lsum += __shfl_xor(lsum, 16);
    lsum += __shfl_xor(lsum, 32);
    float inv = 1.f / lsum;
    float invr[4];
#pragma unroll
    for (int r = 0; r < 4; r++) invr[r] = __shfl(inv, lr * 4 + r);
#pragma unroll
    for (int r = 0; r < 4; r++) {
      int row = b * 1024 + q0 + w * 32 + g * 16 + lr * 4 + r;
#pragma unroll
      for (int nd = 0; nd < 4; nd++)
        O[row * 1024 + h * 64 + nd * 16 + lc] = f2bf(oacc[g][nd][r] * invr[r]);
    }
  }
}

// ---------------- residual + LayerNorm (p2 in bf16) ----------------
__global__ __launch_bounds__(256) void ln_k(const float* __restrict__ q,
                                            const u16* __restrict__ p2,
                                            const float* __restrict__ gamma,
                                            const float* __restrict__ beta,
                                            float* __restrict__ out) {
  const int row = blockIdx.x, tid = threadIdx.x;
  float4 xq = ((const float4*)(q + row * 1024))[tid];
  u16x4 xpb = ((const u16x4*)(p2 + row * 1024))[tid];
  float4 x = {xq.x + bf2f(xpb.x), xq.y + bf2f(xpb.y),
              xq.z + bf2f(xpb.z), xq.w + bf2f(xpb.w)};
  float s = x.x + x.y + x.z + x.w;
#pragma unroll
  for (int off = 1; off < 64; off <<= 1) s += __shfl_xor(s, off);
  __shared__ float red[8];
  const int w = tid >> 6;
  if ((tid & 63) == 0) red[w] = s;
  __syncthreads();
  float mu = (red[0] + red[1] + red[2] + red[3]) * (1.0f / 1024.0f);
  float4 dx = {x.x - mu, x.y - mu, x.z - mu, x.w - mu};
  float s2 = dx.x * dx.x + dx.y * dx.y + dx.z * dx.z + dx.w * dx.w;
#pragma unroll
  for (int off = 1; off < 64; off <<= 1) s2 += __shfl_xor(s2, off);
  if ((tid & 63) == 0) red[4 + w] = s2;
  __syncthreads();
  float var = (red[4] + red[5] + red[6] + red[7]) * (1.0f / 1024.0f);
  float rs = rsqrtf(var + 1e-5f);
  float4 g = ((const float4*)gamma)[tid];
  float4 bb = ((const float4*)beta)[tid];
  float4 o = {dx.x * rs * g.x + bb.x, dx.y * rs * g.y + bb.y,
              dx.z * rs * g.z + bb.z, dx.w * rs * g.w + bb.w};
  ((float4*)(out + row * 1024))[tid] = o;
}

extern "C" void kernel_launch(void* const* d_in, const int* in_sizes, int n_in,
                              void* d_out, int out_size, void* d_ws, size_t ws_size,
                              hipStream_t stream) {
  const float* query = (const float*)d_in[0];
  const float* kv    = (const float*)d_in[1];
  const float* Wq = (const float*)d_in[2];
  const float* bq = (const float*)d_in[3];
  const float* Wk = (const float*)d_in[4];
  const float* bk = (const float*)d_in[5];
  const float* Wv = (const float*)d_in[6];
  const float* bv = (const float*)d_in[7];
  const float* Wo = (const float*)d_in[8];
  const float* bo = (const float*)d_in[9];
  const float* gamma = (const float*)d_in[10];
  const float* beta  = (const float*)d_in[11];
  float* out = (float*)d_out;

  char* ws = (char*)d_ws;
  const size_t MB = 1u << 20;
  u16* qbf  = (u16*)(ws + 0 * MB);
  u16* kvbf = (u16*)(ws + 8 * MB);
  u16* Wqt  = (u16*)(ws + 16 * MB);
  u16* Wkt  = (u16*)(ws + 18 * MB);
  u16* Wvt  = (u16*)(ws + 20 * MB);
  u16* Wot  = (u16*)(ws + 22 * MB);
  u16* Qh   = (u16*)(ws + 24 * MB);
  u16* Kh   = (u16*)(ws + 32 * MB);
  u16* Vth  = (u16*)(ws + 40 * MB);
  u16* attO = (u16*)(ws + 48 * MB);
  u16* p2b  = (u16*)(ws + 56 * MB);

  cvt2_k<<<dim3(8192), dim3(256), 0, stream>>>(query, kv, qbf, kvbf);
  wt_k<<<dim3(16, 16, 4), dim3(256), 0, stream>>>(Wq, Wk, Wv, Wo, Wqt, Wkt, Wvt, Wot);

  gemmqkv_k<<<dim3(768), dim3(256), 0, stream>>>(qbf, kvbf, Wqt, Wkt, Wvt,
                                                 bq, bk, bv, Qh, Kh, Vth);

  attn_k<<<dim3(512), dim3(256), 0, stream>>>(Qh, Kh, Vth, attO);

  gemmo_k<<<dim3(512), dim3(256), 0, stream>>>(attO, Wot, bo, p2b);

  ln_k<<<dim3(4096), dim3(256), 0, stream>>>(query, p2b, gamma, beta, out);
}

// Round 12
// 99.310 us; speedup vs baseline: 1.0439x; 1.0439x over previous
//
#include <hip/hip_runtime.h>

typedef unsigned short u16;
typedef unsigned int u32;
typedef __attribute__((ext_vector_type(2))) unsigned int u32x2;
typedef __attribute__((ext_vector_type(4))) unsigned short u16x4;
typedef __attribute__((ext_vector_type(8))) short short8;
typedef __attribute__((ext_vector_type(4))) float f32x4;

#define MFMA16(a, b, c) __builtin_amdgcn_mfma_f32_16x16x32_bf16(a, b, c, 0, 0, 0)

__device__ __forceinline__ u16 f2bf(float f) {
  unsigned u = __builtin_bit_cast(unsigned, f);
  u += 0x7fffu + ((u >> 16) & 1u);
  return (u16)(u >> 16);
}

__device__ __forceinline__ float bf2f(u16 b) {
  return __builtin_bit_cast(float, ((u32)b) << 16);
}

__device__ __forceinline__ u32 cvtpk(float lo, float hi) {
  u32 r;
  asm("v_cvt_pk_bf16_f32 %0, %1, %2" : "=v"(r) : "v"(lo), "v"(hi));
  return r;
}

__device__ __forceinline__ float ex2(float x) {  // 2^x
  float r;
  asm("v_exp_f32 %0, %1" : "=v"(r) : "v"(x));
  return r;
}

__device__ __forceinline__ void gl_lds16(const void* g, void* l) {
  __builtin_amdgcn_global_load_lds((const __attribute__((address_space(1))) char*)g,
                                   (__attribute__((address_space(3))) char*)l, 16, 0, 0);
}

// ---------------- f32 -> bf16 convert (query + kv in one dispatch) ----------------
__global__ __launch_bounds__(256) void cvt2_k(const float* __restrict__ a,
                                              const float* __restrict__ b,
                                              u16* __restrict__ oa, u16* __restrict__ ob) {
  const int bid = blockIdx.x;
  const float* in = (bid < 4096) ? a : b;
  u16* out = (bid < 4096) ? oa : ob;
  int i = (bid & 4095) * 256 + threadIdx.x;
  float4 v = ((const float4*)in)[i];
  u16x4 o;
  o.x = f2bf(v.x); o.y = f2bf(v.y); o.z = f2bf(v.z); o.w = f2bf(v.w);
  ((u16x4*)out)[i] = o;
}

// ---------------- W[k][n] f32 -> Wt[n][k] bf16 (tiled transpose) ----------------
__global__ __launch_bounds__(256) void wt_k(const float* __restrict__ W0, const float* __restrict__ W1,
                                            const float* __restrict__ W2, const float* __restrict__ W3,
                                            u16* __restrict__ T0, u16* __restrict__ T1,
                                            u16* __restrict__ T2, u16* __restrict__ T3) {
  const float* W; u16* T;
  switch (blockIdx.z) {
    case 0: W = W0; T = T0; break;
    case 1: W = W1; T = T1; break;
    case 2: W = W2; T = T2; break;
    default: W = W3; T = T3; break;
  }
  __shared__ __align__(16) u16 t[64][72];
  const int k0 = blockIdx.y * 64, n0 = blockIdx.x * 64;
  const int tid = threadIdx.x;
  const int r = tid >> 4, c4 = (tid & 15) * 4;
#pragma unroll
  for (int i = 0; i < 4; i++) {
    float4 v = *(const float4*)(W + (k0 + r + i * 16) * 1024 + n0 + c4);
    u16x4 o;
    o.x = f2bf(v.x); o.y = f2bf(v.y); o.z = f2bf(v.z); o.w = f2bf(v.w);
    *(u16x4*)&t[r + i * 16][c4] = o;
  }
  __syncthreads();
#pragma unroll
  for (int i = 0; i < 4; i++) {
    int nr = r + i * 16;
    u16x4 o;
    o.x = t[c4 + 0][nr]; o.y = t[c4 + 1][nr]; o.z = t[c4 + 2][nr]; o.w = t[c4 + 3][nr];
    *(u16x4*)(T + (n0 + nr) * 1024 + k0 + c4) = o;
  }
}

// ---------------- fused QKV projection, 128x128 tile, BK=64, XCD-swizzled ----------------
__global__ __launch_bounds__(256, 3) void gemmqkv_k(
    const u16* __restrict__ qbf, const u16* __restrict__ kvbf,
    const u16* __restrict__ Wqt, const u16* __restrict__ Wkt, const u16* __restrict__ Wvt,
    const float* __restrict__ pbq, const float* __restrict__ pbk, const float* __restrict__ pbv,
    u16* __restrict__ Qh, u16* __restrict__ Kh, u16* __restrict__ Vth) {
  const int lin = blockIdx.x;
  const int swz = (lin & 7) * 96 + (lin >> 3);
  const int x = swz & 7, y = (swz >> 3) & 31, z = swz >> 8;

  const u16* A  = (z == 0) ? qbf : kvbf;
  const u16* Bt = (z == 0) ? Wqt : (z == 1 ? Wkt : Wvt);
  const float* bias = (z == 0) ? pbq : (z == 1 ? pbk : pbv);

  __shared__ __align__(16) u16 As[128 * 64];  // two [128][32] halves
  __shared__ __align__(16) u16 Bs[128 * 64];
  const int tid = threadIdx.x;
  const int l = tid & 63, w = tid >> 6;
  const int lr = l >> 4, lc = l & 15;
  const int wr = w >> 1, wc = w & 1;
  const int m0 = y * 128, n0 = x * 128;

  f32x4 acc[4][4] = {};

  const int sr = tid >> 2, sc = (tid & 3) * 8;
  const u16* Ag = A + (m0 + sr) * 1024 + sc;
  const u16* Bg = Bt + (n0 + sr) * 1024 + sc;

  for (int k0 = 0; k0 < 1024; k0 += 64) {
    __syncthreads();
    gl_lds16(Ag + k0, As + tid * 8);
    gl_lds16(Ag + 64 * 1024 + k0, As + 2048 + tid * 8);
    gl_lds16(Bg + k0, Bs + tid * 8);
    gl_lds16(Bg + 64 * 1024 + k0, Bs + 2048 + tid * 8);
    gl_lds16(Ag + k0 + 32, As + 4096 + tid * 8);
    gl_lds16(Ag + 64 * 1024 + k0 + 32, As + 6144 + tid * 8);
    gl_lds16(Bg + k0 + 32, Bs + 4096 + tid * 8);
    gl_lds16(Bg + 64 * 1024 + k0 + 32, Bs + 6144 + tid * 8);
    __syncthreads();
    const u16* PA = (z == 2) ? Bs : As;
    const u16* PB = (z == 2) ? As : Bs;
    short8 af[4][2], bf[4][2];
    const int ks8 = lr * 8;
#pragma unroll
    for (int m = 0; m < 4; m++)
#pragma unroll
      for (int h = 0; h < 2; h++)
        af[m][h] = *(const short8*)(PA + h * 4096 + (wr * 64 + m * 16 + lc) * 32 + ks8);
#pragma unroll
    for (int n = 0; n < 4; n++)
#pragma unroll
      for (int h = 0; h < 2; h++)
        bf[n][h] = *(const short8*)(PB + h * 4096 + (wc * 64 + n * 16 + lc) * 32 + ks8);
#pragma unroll
    for (int m = 0; m < 4; m++)
#pragma unroll
      for (int n = 0; n < 4; n++) {
        acc[m][n] = MFMA16(af[m][0], bf[n][0], acc[m][n]);
        acc[m][n] = MFMA16(af[m][1], bf[n][1], acc[m][n]);
      }
  }

  if (z == 2) {  // V^T: acc rows = channel, cols = token
#pragma unroll
    for (int m = 0; m < 4; m++) {
#pragma unroll
      for (int r = 0; r < 4; r++) {
        int ncol = n0 + wr * 64 + m * 16 + lr * 4 + r;
        float bb = bias[ncol];
        int h = ncol >> 6, d = ncol & 63;
#pragma unroll
        for (int n = 0; n < 4; n++) {
          int tok = m0 + wc * 64 + n * 16 + lc;
          Vth[(((tok >> 10) * 16 + h) * 64 + d) * 1024 + (tok & 1023)] =
              f2bf(acc[m][n][r] + bb);
        }
      }
    }
  } else {
    u16* outb = (z == 0) ? Qh : Kh;
    const float scale = (z == 0) ? 0.18033688f : 1.0f;  // 0.125 * log2(e)
#pragma unroll
    for (int m = 0; m < 4; m++)
#pragma unroll
      for (int n = 0; n < 4; n++) {
        int ncol = n0 + wc * 64 + n * 16 + lc;
        float bb = bias[ncol];
        int h = ncol >> 6, d = ncol & 63;
#pragma unroll
        for (int r = 0; r < 4; r++) {
          int tok = m0 + wr * 64 + m * 16 + lr * 4 + r;
          outb[(((tok >> 10) * 16 + h) * 1024 + (tok & 1023)) * 64 + d] =
              f2bf((acc[m][n][r] + bb) * scale);
        }
      }
  }
}

// ---------------- output projection, 128x64 tile, BK=64 -> bf16, XCD-swizzled ----------------
__global__ __launch_bounds__(256, 4) void gemmo_k(const u16* __restrict__ A,
                                                  const u16* __restrict__ Bt,
                                                  const float* __restrict__ bias,
                                                  u16* __restrict__ outb) {
  const int lin = blockIdx.x;
  const int swz = (lin & 7) * 64 + (lin >> 3);
  const int x = swz & 15, y = swz >> 4;

  __shared__ __align__(16) u16 As[128 * 64];  // two [128][32] halves
  __shared__ __align__(16) u16 Bs[64 * 64];   // two [64][32] halves
  const int tid = threadIdx.x;
  const int l = tid & 63, w = tid >> 6;
  const int lr = l >> 4, lc = l & 15;
  const int wr = w >> 1, wc = w & 1;
  const int m0 = y * 128, n0 = x * 64;

  f32x4 acc[4][2] = {};
  const int sc = (tid & 3) * 8;
  const u16* Ag = A + (m0 + (tid >> 2)) * 1024 + sc;
  const u16* Bg = Bt + (n0 + (tid >> 2)) * 1024 + sc;

  for (int k0 = 0; k0 < 1024; k0 += 64) {
    __syncthreads();
    gl_lds16(Ag + k0, As + tid * 8);
    gl_lds16(Ag + 64 * 1024 + k0, As + 2048 + tid * 8);
    gl_lds16(Bg + k0, Bs + tid * 8);
    gl_lds16(Ag + k0 + 32, As + 4096 + tid * 8);
    gl_lds16(Ag + 64 * 1024 + k0 + 32, As + 6144 + tid * 8);
    gl_lds16(Bg + k0 + 32, Bs + 2048 + tid * 8);
    __syncthreads();
    short8 af[4][2], bf[2][2];
    const int ks8 = lr * 8;
#pragma unroll
    for (int m = 0; m < 4; m++)
#pragma unroll
      for (int h = 0; h < 2; h++)
        af[m][h] = *(const short8*)(As + h * 4096 + (wr * 64 + m * 16 + lc) * 32 + ks8);
#pragma unroll
    for (int n = 0; n < 2; n++)
#pragma unroll
      for (int h = 0; h < 2; h++)
        bf[n][h] = *(const short8*)(Bs + h * 2048 + (wc * 32 + n * 16 + lc) * 32 + ks8);
#pragma unroll
    for (int m = 0; m < 4; m++)
#pragma unroll
      for (int n = 0; n < 2; n++) {
        acc[m][n] = MFMA16(af[m][0], bf[n][0], acc[m][n]);
        acc[m][n] = MFMA16(af[m][1], bf[n][1], acc[m][n]);
      }
  }
#pragma unroll
  for (int m = 0; m < 4; m++)
#pragma unroll
    for (int n = 0; n < 2; n++) {
      int ncol = n0 + wc * 32 + n * 16 + lc;
      float bb = bias[ncol];
#pragma unroll
      for (int r = 0; r < 4; r++) {
        int tok = m0 + wr * 64 + m * 16 + lr * 4 + r;
        outb[tok * 1024 + ncol] = f2bf(acc[m][n][r] + bb);
      }
    }
}

// ---------------- flash attention: QBLK=128, ones-MFMA row sums ----------------
// Softmax row-sum moved to the matrix pipe: sacc = mfma(P, ones, sacc). No VALU
// sum, no epilogue sum-shuffles; sums land in oacc row layout directly.
__global__ __launch_bounds__(256, 2) void attn_k(const u16* __restrict__ Q,
                                                 const u16* __restrict__ K,
                                                 const u16* __restrict__ Vt,
                                                 u16* __restrict__ O) {
  const int bid = blockIdx.x;          // 512 blocks
  const int xcd = bid & 7, j = bid >> 3;
  const int bh = xcd + 8 * (j & 7);    // 8 heads per XCD
  const int q0 = (j >> 3) * 128;       // 8 q-blocks of 128
  const int tid = threadIdx.x;
  const int w = tid >> 6, l = tid & 63;
  const int lr = l >> 4, lc = l & 15;
  const u16* Qh = Q + bh * (1024 * 64);
  const u16* Kh = K + bh * (1024 * 64);
  const u16* Vh = Vt + bh * (64 * 1024);

  __shared__ __align__(16) u16 Ks[2][64 * 64];      // 16 KB
  __shared__ __align__(16) u16 Vs[2][64 * 64];      // 16 KB
  __shared__ __align__(16) u32 Plds[4][2][16][32];  // 16 KB, XOR-swizzled slots

  const int st_row = tid >> 3;
  const int st_cb = (tid & 7) * 16;
  const int sw1 = (st_cb ^ ((st_row & 7) << 4)) >> 1;
  const int st_row2 = st_row + 32;
  const int sw2 = (st_cb ^ ((st_row2 & 7) << 4)) >> 1;

  // all-ones bf16 B-fragment (1.0 = 0x3F80)
  const short8 ones = {0x3F80, 0x3F80, 0x3F80, 0x3F80, 0x3F80, 0x3F80, 0x3F80, 0x3F80};

  // Q fragments: 2 q-groups x 2 k-slices
  short8 bq[2][2];
#pragma unroll
  for (int g = 0; g < 2; g++)
#pragma unroll
    for (int ks = 0; ks < 2; ks++)
      bq[g][ks] = *(const short8*)(Qh + (q0 + w * 32 + g * 16 + lc) * 64 + ks * 32 + lr * 8);

  f32x4 oacc[2][4] = {};
  f32x4 sacc[2] = {};                 // row-sum accumulator (MFMA, row layout)
  float mrun[2] = {-1e30f, -1e30f};   // per-q running max (log2 domain)

  // prologue: stage tile 0 into buffer 0
  gl_lds16(Kh + st_row * 64 + sw1, &Ks[0][tid * 8]);
  gl_lds16(Kh + st_row2 * 64 + sw2, &Ks[0][2048 + tid * 8]);
  gl_lds16(Vh + st_row * 1024 + sw1, &Vs[0][tid * 8]);
  gl_lds16(Vh + st_row2 * 1024 + sw2, &Vs[0][2048 + tid * 8]);

  const int xw = (lc & 7) << 2;  // P-LDS XOR

  for (int t = 0; t < 16; ++t) {
    const int pb = t & 1;
    if (t < 15) {
      const int kvn = (t + 1) * 64;
      gl_lds16(Kh + (kvn + st_row) * 64 + sw1, &Ks[pb ^ 1][tid * 8]);
      gl_lds16(Kh + (kvn + st_row2) * 64 + sw2, &Ks[pb ^ 1][2048 + tid * 8]);
      gl_lds16(Vh + st_row * 1024 + kvn + sw1, &Vs[pb ^ 1][tid * 8]);
      gl_lds16(Vh + st_row2 * 1024 + kvn + sw2, &Vs[pb ^ 1][2048 + tid * 8]);
      asm volatile("s_waitcnt vmcnt(4)" ::: "memory");  // tile t landed; t+1 in flight
    } else {
      asm volatile("s_waitcnt vmcnt(0)" ::: "memory");
    }
    __builtin_amdgcn_s_barrier();
    asm volatile("" ::: "memory");

    const u16* Kb = Ks[pb];
    const u16* Vb = Vs[pb];

    // S^T = K . Q^T for both q-groups; each K fragment read feeds 2 MFMAs
    f32x4 s0[4] = {}, s1[4] = {};
    __builtin_amdgcn_s_setprio(1);
#pragma unroll
    for (int mk = 0; mk < 4; mk++) {
      const int krow = mk * 16 + lc;
      const u16* kp = Kb + krow * 64;
#pragma unroll
      for (int ks = 0; ks < 2; ks++) {
        const int cb = (ks * 64 + lr * 16) ^ ((krow & 7) << 4);
        short8 ak = *(const short8*)(kp + (cb >> 1));
        s0[mk] = MFMA16(ak, bq[0][ks], s0[mk]);
        s1[mk] = MFMA16(ak, bq[1][ks], s1[mk]);
      }
    }
    __builtin_amdgcn_s_setprio(0);

    // per-lane local max over own 16 values (tree, no shuffles)
    float mx0, mx1;
    {
      float a = fmaxf(fmaxf(s0[0][0], s0[0][1]), fmaxf(s0[0][2], s0[0][3]));
      float b = fmaxf(fmaxf(s0[1][0], s0[1][1]), fmaxf(s0[1][2], s0[1][3]));
      float c = fmaxf(fmaxf(s0[2][0], s0[2][1]), fmaxf(s0[2][2], s0[2][3]));
      float d = fmaxf(fmaxf(s0[3][0], s0[3][1]), fmaxf(s0[3][2], s0[3][3]));
      mx0 = fmaxf(fmaxf(a, b), fmaxf(c, d));
      float e = fmaxf(fmaxf(s1[0][0], s1[0][1]), fmaxf(s1[0][2], s1[0][3]));
      float f = fmaxf(fmaxf(s1[1][0], s1[1][1]), fmaxf(s1[1][2], s1[1][3]));
      float g2 = fmaxf(fmaxf(s1[2][0], s1[2][1]), fmaxf(s1[2][2], s1[2][3]));
      float h = fmaxf(fmaxf(s1[3][0], s1[3][1]), fmaxf(s1[3][2], s1[3][3]));
      mx1 = fmaxf(fmaxf(e, f), fmaxf(g2, h));
    }

    // shuffle-free defer-max: decision via __all on per-lane maxima.
    if (!__all(mx0 <= mrun[0] + 8.f && mx1 <= mrun[1] + 8.f)) {
      mx0 = fmaxf(mx0, __shfl_xor(mx0, 16));
      mx0 = fmaxf(mx0, __shfl_xor(mx0, 32));
      mx1 = fmaxf(mx1, __shfl_xor(mx1, 16));
      mx1 = fmaxf(mx1, __shfl_xor(mx1, 32));
      float mn0 = fmaxf(mrun[0], mx0), mn1 = fmaxf(mrun[1], mx1);
      float al0 = ex2(mrun[0] - mn0), al1 = ex2(mrun[1] - mn1);
      mrun[0] = mn0; mrun[1] = mn1;
      float a0[4], a1[4];
#pragma unroll
      for (int r = 0; r < 4; r++) {
        a0[r] = __shfl(al0, lr * 4 + r);
        a1[r] = __shfl(al1, lr * 4 + r);
      }
#pragma unroll
      for (int r = 0; r < 4; r++) {
        sacc[0][r] *= a0[r];
        sacc[1][r] *= a1[r];
      }
#pragma unroll
      for (int nd = 0; nd < 4; nd++)
#pragma unroll
        for (int r = 0; r < 4; r++) {
          oacc[0][nd][r] *= a0[r];
          oacc[1][nd][r] *= a1[r];
        }
    }

    // P = 2^(S - m) (no VALU sums — sums go through the ones-MFMA)
#pragma unroll
    for (int mk = 0; mk < 4; mk++)
#pragma unroll
      for (int r = 0; r < 4; r++) {
        s0[mk][r] = ex2(s0[mk][r] - mrun[0]);
        s1[mk][r] = ex2(s1[mk][r] - mrun[1]);
      }

    // pack P -> per-wave LDS, b64 writes
    u32* PW0 = &Plds[w][0][lc][0];
    u32* PW1 = &Plds[w][1][lc][0];
#pragma unroll
    for (int mk = 0; mk < 4; mk++) {
      const int idx = (mk * 8 + lr * 2) ^ xw;
      u32x2 p0 = {cvtpk(s0[mk][0], s0[mk][1]), cvtpk(s0[mk][2], s0[mk][3])};
      u32x2 p1 = {cvtpk(s1[mk][0], s1[mk][1]), cvtpk(s1[mk][2], s1[mk][3])};
      *(u32x2*)&PW0[idx] = p0;
      *(u32x2*)&PW1[idx] = p1;
    }

    // O += P V ; row sums += P . ones  (each V fragment read feeds 2 MFMAs)
    __builtin_amdgcn_s_setprio(1);
#pragma unroll
    for (int ks = 0; ks < 2; ks++) {
      short8 ap0 = *(const short8*)&Plds[w][0][lc][(ks * 16 + lr * 4) ^ xw];
      short8 ap1 = *(const short8*)&Plds[w][1][lc][(ks * 16 + lr * 4) ^ xw];
      sacc[0] = MFMA16(ap0, ones, sacc[0]);
      sacc[1] = MFMA16(ap1, ones, sacc[1]);
#pragma unroll
      for (int nd = 0; nd < 4; nd++) {
        const int vrow = nd * 16 + lc;
        const int cb = (ks * 64 + lr * 16) ^ ((vrow & 7) << 4);
        short8 bv = *(const short8*)(Vb + vrow * 64 + (cb >> 1));
        oacc[0][nd] = MFMA16(ap0, bv, oacc[0][nd]);
        oacc[1][nd] = MFMA16(ap1, bv, oacc[1][nd]);
      }
    }
    __builtin_amdgcn_s_setprio(0);

    asm volatile("" ::: "memory");
    __builtin_amdgcn_s_barrier();  // all waves done reading Ks[pb]/Vs[pb]
  }

  // epilogue: sums are already in row layout (all cols identical)
  const int b = bh >> 4, h = bh & 15;
#pragma unroll
  for (int g = 0; g < 2; g++) {
    float invr[4];
#pragma unroll
    for (int r = 0; r < 4; r++) invr[r] = 1.f / sacc[g][r];
#pragma unroll
    for (int r = 0; r < 4; r++) {
      int row = b * 1024 + q0 + w * 32 + g * 16 + lr * 4 + r;
#pragma unroll
      for (int nd = 0; nd < 4; nd++)
        O[row * 1024 + h * 64 + nd * 16 + lc] = f2bf(oacc[g][nd][r] * invr[r]);
    }
  }
}

// ---------------- residual + LayerNorm (p2 in bf16) ----------------
__global__ __launch_bounds__(256) void ln_k(const float* __restrict__ q,
                                            const u16* __restrict__ p2,
                                            const float* __restrict__ gamma,
                                            const float* __restrict__ beta,
                                            float* __restrict__ out) {
  const int row = blockIdx.x, tid = threadIdx.x;
  float4 xq = ((const float4*)(q + row * 1024))[tid];
  u16x4 xpb = ((const u16x4*)(p2 + row * 1024))[tid];
  float4 x = {xq.x + bf2f(xpb.x), xq.y + bf2f(xpb.y),
              xq.z + bf2f(xpb.z), xq.w + bf2f(xpb.w)};
  float s = x.x + x.y + x.z + x.w;
#pragma unroll
  for (int off = 1; off < 64; off <<= 1) s += __shfl_xor(s, off);
  __shared__ float red[8];
  const int w = tid >> 6;
  if ((tid & 63) == 0) red[w] = s;
  __syncthreads();
  float mu = (red[0] + red[1] + red[2] + red[3]) * (1.0f / 1024.0f);
  float4 dx = {x.x - mu, x.y - mu, x.z - mu, x.w - mu};
  float s2 = dx.x * dx.x + dx.y * dx.y + dx.z * dx.z + dx.w * dx.w;
#pragma unroll
  for (int off = 1; off < 64; off <<= 1) s2 += __shfl_xor(s2, off);
  if ((tid & 63) == 0) red[4 + w] = s2;
  __syncthreads();
  float var = (red[4] + red[5] + red[6] + red[7]) * (1.0f / 1024.0f);
  float rs = rsqrtf(var + 1e-5f);
  float4 g = ((const float4*)gamma)[tid];
  float4 bb = ((const float4*)beta)[tid];
  float4 o = {dx.x * rs * g.x + bb.x, dx.y * rs * g.y + bb.y,
              dx.z * rs * g.z + bb.z, dx.w * rs * g.w + bb.w};
  ((float4*)(out + row * 1024))[tid] = o;
}

extern "C" void kernel_launch(void* const* d_in, const int* in_sizes, int n_in,
                              void* d_out, int out_size, void* d_ws, size_t ws_size,
                              hipStream_t stream) {
  const float* query = (const float*)d_in[0];
  const float* kv    = (const float*)d_in[1];
  const float* Wq = (const float*)d_in[2];
  const float* bq = (const float*)d_in[3];
  const float* Wk = (const float*)d_in[4];
  const float* bk = (const float*)d_in[5];
  const float* Wv = (const float*)d_in[6];
  const float* bv = (const float*)d_in[7];
  const float* Wo = (const float*)d_in[8];
  const float* bo = (const float*)d_in[9];
  const float* gamma = (const float*)d_in[10];
  const float* beta  = (const float*)d_in[11];
  float* out = (float*)d_out;

  char* ws = (char*)d_ws;
  const size_t MB = 1u << 20;
  u16* qbf  = (u16*)(ws + 0 * MB);
  u16* kvbf = (u16*)(ws + 8 * MB);
  u16* Wqt  = (u16*)(ws + 16 * MB);
  u16* Wkt  = (u16*)(ws + 18 * MB);
  u16* Wvt  = (u16*)(ws + 20 * MB);
  u16* Wot  = (u16*)(ws + 22 * MB);
  u16* Qh   = (u16*)(ws + 24 * MB);
  u16* Kh   = (u16*)(ws + 32 * MB);
  u16* Vth  = (u16*)(ws + 40 * MB);
  u16* attO = (u16*)(ws + 48 * MB);
  u16* p2b  = (u16*)(ws + 56 * MB);

  cvt2_k<<<dim3(8192), dim3(256), 0, stream>>>(query, kv, qbf, kvbf);
  wt_k<<<dim3(16, 16, 4), dim3(256), 0, stream>>>(Wq, Wk, Wv, Wo, Wqt, Wkt, Wvt, Wot);

  gemmqkv_k<<<dim3(768), dim3(256), 0, stream>>>(qbf, kvbf, Wqt, Wkt, Wvt,
                                                 bq, bk, bv, Qh, Kh, Vth);

  attn_k<<<dim3(512), dim3(256), 0, stream>>>(Qh, Kh, Vth, attO);

  gemmo_k<<<dim3(512), dim3(256), 0, stream>>>(attO, Wot, bo, p2b);

  ln_k<<<dim3(4096), dim3(256), 0, stream>>>(query, p2b, gamma, beta, out);
}